// Round 3
// baseline (905.381 us; speedup 1.0000x reference)
//
#include <hip/hip_runtime.h>

// ---------------- common helpers ----------------
typedef __attribute__((ext_vector_type(8))) short short8;
typedef __attribute__((ext_vector_type(4))) float f32x4;
typedef __attribute__((ext_vector_type(2))) float f32x2;
typedef __attribute__((ext_vector_type(4))) unsigned short us4;

#define B_SZ 512
#define T_SZ 512
#define M_SZ (B_SZ * T_SZ)   // 262144 rows

__device__ __forceinline__ unsigned short f2bf(float f) {
    union { float f; unsigned u; } v; v.f = f;
    unsigned r = v.u + 0x7FFFu + ((v.u >> 16) & 1u);   // RNE
    return (unsigned short)(r >> 16);
}
__device__ __forceinline__ float bf2f(unsigned short b) {
    union { unsigned u; float f; } v; v.u = ((unsigned)b) << 16;
    return v.f;
}
__device__ __forceinline__ float rcp_(float x) { return __builtin_amdgcn_rcpf(x); }
__device__ __forceinline__ float sigm_(float x) { return rcp_(1.f + __expf(-x)); }
__device__ __forceinline__ float tanh_s(float x) {   // overflow-safe tanh
    float ax = fminf(fabsf(x), 15.f);
    float e2 = __expf(2.f * ax);
    float t = (e2 - 1.f) * rcp_(e2 + 1.f);
    return x < 0.f ? -t : t;
}
__device__ __forceinline__ short8 cvt8(float4 a, float4 b) {
    short8 r;
    r[0] = (short)f2bf(a.x); r[1] = (short)f2bf(a.y); r[2] = (short)f2bf(a.z); r[3] = (short)f2bf(a.w);
    r[4] = (short)f2bf(b.x); r[5] = (short)f2bf(b.y); r[6] = (short)f2bf(b.z); r[7] = (short)f2bf(b.w);
    return r;
}

// ---------------- weight prep: concat fwd/bwd w_ih -> bf16 [8H][K], bias = b_ih+b_hh ----------------
__global__ __launch_bounds__(256) void prep_layer(
        const float* __restrict__ wf, const float* __restrict__ wb,
        const float* __restrict__ bif, const float* __restrict__ bhf,
        const float* __restrict__ bib, const float* __restrict__ bhb,
        unsigned short* __restrict__ wcat, float* __restrict__ bias,
        int n /*4H*K*/, int fourH) {
    int stride = gridDim.x * blockDim.x;
    for (int i = blockIdx.x * blockDim.x + threadIdx.x; i < 2 * n; i += stride)
        wcat[i] = f2bf(i < n ? wf[i] : wb[i - n]);
    for (int i = blockIdx.x * blockDim.x + threadIdx.x; i < 2 * fourH; i += stride)
        bias[i] = (i < fourH) ? (bif[i] + bhf[i]) : (bib[i - fourH] + bhb[i - fourH]);
}

// ---------------- gx store: chunk-interleaved layout gxc[b][t>>3][g][t&7] ----------------
// Backward-gate rows (rev) are stored TIME-REVERSED so the scan always reads forward.
__device__ __forceinline__ void store_gx(unsigned short* __restrict__ outC, int N,
                                         int b, int tl, int col, bool rev,
                                         f32x4 acc, float bv) {
    if (!rev) {
        us4 v = { f2bf(acc[0]+bv), f2bf(acc[1]+bv), f2bf(acc[2]+bv), f2bf(acc[3]+bv) };
        *(us4*)(outC + (((size_t)b * 64 + (tl >> 3)) * (size_t)N + col) * 8 + (tl & 7)) = v;
    } else {
        int p = T_SZ - 4 - tl;
        us4 v = { f2bf(acc[3]+bv), f2bf(acc[2]+bv), f2bf(acc[1]+bv), f2bf(acc[0]+bv) };
        *(us4*)(outC + (((size_t)b * 64 + (p >> 3)) * (size_t)N + col) * 8 + (p & 7)) = v;
    }
}

// ---------------- layer-1 GEMM: A = x in f32 (cast fused), W bf16 [N][K] ----------------
template<int K, int N>
__global__ __launch_bounds__(256) void gemm_gx_f32(const float* __restrict__ A,
                                                   const unsigned short* __restrict__ W,
                                                   const float* __restrict__ bias,
                                                   unsigned short* __restrict__ outC) {
    constexpr int TN = N / 16;
    int slot = threadIdx.x >> 6, l = threadIdx.x & 63;
    int wv = blockIdx.x * 4 + slot;
    int tg = wv / TN, tn = wv % TN;
    int rowb = tg * 64;
    int col = tn * 16 + (l & 15);
    int kq = (l >> 4) * 8;
    f32x4 acc0 = {0,0,0,0}, acc1 = {0,0,0,0}, acc2 = {0,0,0,0}, acc3 = {0,0,0,0};
    const unsigned short* wp = W + (size_t)col * K + kq;
    const float* ap = A + ((size_t)rowb + (l & 15)) * K + kq;
#pragma unroll
    for (int kk = 0; kk < K; kk += 32) {
        short8 bfrag = *(const short8*)(wp + kk);
        short8 a0 = cvt8(*(const float4*)(ap + kk),                    *(const float4*)(ap + kk + 4));
        short8 a1 = cvt8(*(const float4*)(ap + (size_t)16*K + kk),     *(const float4*)(ap + (size_t)16*K + kk + 4));
        short8 a2 = cvt8(*(const float4*)(ap + (size_t)32*K + kk),     *(const float4*)(ap + (size_t)32*K + kk + 4));
        short8 a3 = cvt8(*(const float4*)(ap + (size_t)48*K + kk),     *(const float4*)(ap + (size_t)48*K + kk + 4));
        acc0 = __builtin_amdgcn_mfma_f32_16x16x32_bf16(a0, bfrag, acc0, 0, 0, 0);
        acc1 = __builtin_amdgcn_mfma_f32_16x16x32_bf16(a1, bfrag, acc1, 0, 0, 0);
        acc2 = __builtin_amdgcn_mfma_f32_16x16x32_bf16(a2, bfrag, acc2, 0, 0, 0);
        acc3 = __builtin_amdgcn_mfma_f32_16x16x32_bf16(a3, bfrag, acc3, 0, 0, 0);
    }
    float bv = bias[col];
    int b = rowb >> 9;
    int tbase = (rowb & 511) + (l >> 4) * 4;
    bool rev = (col >= N / 2);
    store_gx(outC, N, b, tbase,      col, rev, acc0, bv);
    store_gx(outC, N, b, tbase + 16, col, rev, acc1, bv);
    store_gx(outC, N, b, tbase + 32, col, rev, acc2, bv);
    store_gx(outC, N, b, tbase + 48, col, rev, acc3, bv);
}

// ---------------- layers 2/3 GEMM: A split into fwd/bwd bf16 halves [M][HALF] each ----------------
template<int K, int N>
__global__ __launch_bounds__(256) void gemm_gx_split(const unsigned short* __restrict__ AF,
                                                     const unsigned short* __restrict__ AB,
                                                     const unsigned short* __restrict__ W,
                                                     const float* __restrict__ bias,
                                                     unsigned short* __restrict__ outC) {
    constexpr int TN = N / 16;
    constexpr int HALF = K / 2;
    int slot = threadIdx.x >> 6, l = threadIdx.x & 63;
    int wv = blockIdx.x * 4 + slot;
    int tg = wv / TN, tn = wv % TN;
    int rowb = tg * 64;
    int col = tn * 16 + (l & 15);
    int kq = (l >> 4) * 8;
    f32x4 acc0 = {0,0,0,0}, acc1 = {0,0,0,0}, acc2 = {0,0,0,0}, acc3 = {0,0,0,0};
    const unsigned short* wp = W + (size_t)col * K + kq;
    size_t row = (size_t)rowb + (l & 15);
    const unsigned short* baseF = AF + row * HALF;
    const unsigned short* baseB = AB + row * HALF;
#pragma unroll
    for (int kk = 0; kk < K; kk += 32) {
        int ka = kq + kk;
        const unsigned short* pb = (ka < HALF) ? (baseF + ka) : (baseB + ka - HALF);
        short8 bfrag = *(const short8*)(wp + kk);
        short8 a0 = *(const short8*)(pb);
        short8 a1 = *(const short8*)(pb + (size_t)16 * HALF);
        short8 a2 = *(const short8*)(pb + (size_t)32 * HALF);
        short8 a3 = *(const short8*)(pb + (size_t)48 * HALF);
        acc0 = __builtin_amdgcn_mfma_f32_16x16x32_bf16(a0, bfrag, acc0, 0, 0, 0);
        acc1 = __builtin_amdgcn_mfma_f32_16x16x32_bf16(a1, bfrag, acc1, 0, 0, 0);
        acc2 = __builtin_amdgcn_mfma_f32_16x16x32_bf16(a2, bfrag, acc2, 0, 0, 0);
        acc3 = __builtin_amdgcn_mfma_f32_16x16x32_bf16(a3, bfrag, acc3, 0, 0, 0);
    }
    float bv = bias[col];
    int b = rowb >> 9;
    int tbase = (rowb & 511) + (l >> 4) * 4;
    bool rev = (col >= N / 2);
    store_gx(outC, N, b, tbase,      col, rev, acc0, bv);
    store_gx(outC, N, b, tbase + 16, col, rev, acc1, bv);
    store_gx(outC, N, b, tbase + 32, col, rev, acc2, bv);
    store_gx(outC, N, b, tbase + 48, col, rev, acc3, bv);
}

// ---------------- LSTM scan: one wave per (batch, direction), register-only h broadcast ----------------
// gxc: bf16 [b][ch][8H][8]  (rows 0..4H-1 fwd, 4H..8H-1 bwd; bwd rows time-reversed)
// hF/hB: bf16 [b][t][H] at ORIGINAL time positions.
template<int H>
__global__ __launch_bounds__(256, 1) void lstm_scan(const unsigned short* __restrict__ gxc,
                                                    const float* __restrict__ whhf,
                                                    const float* __restrict__ whhb,
                                                    unsigned short* __restrict__ hF,
                                                    unsigned short* __restrict__ hB) {
    constexpr int T = T_SZ;
    constexpr int G4 = 4 * H, G8 = 8 * H;
    int l = threadIdx.x & 63, slot = threadIdx.x >> 6;
    int wv = blockIdx.x * 4 + slot;          // 0..1023
    int b = wv >> 1, dir = wv & 1;
    const float* whh = dir ? whhb : whhf;
    unsigned short* hD = dir ? hB : hF;
    __shared__ float hbuf[4][8][32];

    int rA, q = 0;
    if constexpr (H == 32)      { rA = l; }
    else if constexpr (H == 16) { rA = l;      q = l >> 4; }
    else                        { rA = l & 31; q = (l >> 3) & 3; }

    // recurrent weights pinned in VGPRs as packed pairs
    f32x2 wA2[H / 2];
    const f32x2* wrA = (const f32x2*)(whh + rA * H);
#pragma unroll
    for (int k = 0; k < H / 2; k++) wA2[k] = wrA[k];
    f32x2 wB2[(H == 32) ? 16 : 1];
    if constexpr (H == 32) {
        const f32x2* wrB = (const f32x2*)(whh + (64 + rA) * H);
#pragma unroll
        for (int k = 0; k < 16; k++) wB2[k] = wrB[k];
    }

    const unsigned short* gpA = gxc + ((size_t)b * 64 * G8 + (size_t)dir * G4 + rA) * 8;
    const unsigned short* gpB = gpA + (size_t)64 * 8;   // H==32 second gate row

    float c = 0.f, h = 0.f;
    short8 bufA = *(const short8*)gpA;
    short8 bufB;
    if constexpr (H == 32) bufB = *(const short8*)gpB;

    for (int ch = 0; ch < T / 8; ch++) {
        short8 curA = bufA, curB;
        if constexpr (H == 32) curB = bufB;
        if (ch + 1 < T / 8) {                // prefetch next 8-step chunk (coalesced 16B/lane)
            bufA = *(const short8*)(gpA + (size_t)(ch + 1) * G8 * 8);
            if constexpr (H == 32) bufB = *(const short8*)(gpB + (size_t)(ch + 1) * G8 * 8);
        }
#pragma unroll
        for (int u = 0; u < 8; u++) {
            float g0 = bf2f((unsigned short)curA[u]);
            float g1 = 0.f;
            if constexpr (H == 32) g1 = bf2f((unsigned short)curB[u]);

            // h broadcast via register shuffles + packed FMA dot
            {
                f32x2 ac0 = {0,0}, ac1 = {0,0}, bc0 = {0,0}, bc1 = {0,0};
#pragma unroll
                for (int k2 = 0; k2 < H / 2; k2++) {
                    f32x2 hh = { __shfl(h, 2*k2, 64), __shfl(h, 2*k2 + 1, 64) };
                    if (k2 & 1) { ac1 += wA2[k2] * hh; if constexpr (H == 32) bc1 += wB2[k2] * hh; }
                    else        { ac0 += wA2[k2] * hh; if constexpr (H == 32) bc0 += wB2[k2] * hh; }
                }
                g0 += (ac0.x + ac0.y) + (ac1.x + ac1.y);
                if constexpr (H == 32) g1 += (bc0.x + bc0.y) + (bc1.x + bc1.y);
            }

            float iv, fv, gv, ov;
            if constexpr (H == 32) {
                // lanes 0-31: aA=i(sigm), aB=g(tanh); lanes 32-63: aA=f(sigm), aB=o(sigm)
                float aA = sigm_(g0);
                bool up = (l >= 32);
                float g1c = fminf(fmaxf(g1, -15.f), 15.f);
                float ee = __expf(up ? -g1 : 2.f * g1c);
                float r = rcp_(1.f + ee);
                float aB = up ? r : (ee - 1.f) * r;
                float xA = __shfl_xor(aA, 32, 64);
                float xB = __shfl_xor(aB, 32, 64);
                iv = up ? xA : aA;
                fv = up ? aA : xA;
                gv = up ? xB : aB;
                ov = up ? aB : xB;
            } else {
                // one gate per lane; quarter q in {0,1,2,3} = {i,f,g,o}
                float g0c = fminf(fmaxf(g0, -15.f), 15.f);
                float ee = __expf(q == 2 ? 2.f * g0c : -g0);
                float r = rcp_(1.f + ee);
                float a = (q == 2) ? (ee - 1.f) * r : r;
                constexpr int sh = H;  // 16 or 8
                float v1 = __shfl_xor(a, sh, 64);       // q^1
                float v2 = __shfl_xor(a, 2 * sh, 64);   // q^2
                float v3 = __shfl_xor(a, 3 * sh, 64);   // q^3
                iv = q == 0 ? a  : q == 1 ? v1 : q == 2 ? v2 : v3;
                fv = q == 0 ? v1 : q == 1 ? a  : q == 2 ? v3 : v2;
                gv = q == 0 ? v2 : q == 1 ? v3 : q == 2 ? a  : v1;
                ov = q == 0 ? v3 : q == 1 ? v2 : q == 2 ? v1 : a;
            }

            c = fmaf(fv, c, iv * gv);
            h = ov * tanh_s(c);

            if (l < H) hbuf[slot][u][l] = h;   // stage for coalesced flush
        }
        // flush 8 steps of h: coalesced bf16 stores at original time positions
        {
            constexpr int GPT = H / 4;         // lane-groups per timestep
            if (l < 8 * GPT) {
                int tt = l / GPT;
                int j0 = (l % GPT) * 4;
                int us = dir ? (7 - tt) : tt;
                int t  = (dir ? (T - 8 - ch * 8) : ch * 8) + tt;
                float4 hv4 = *(const float4*)&hbuf[slot][us][j0];
                us4 o = { f2bf(hv4.x), f2bf(hv4.y), f2bf(hv4.z), f2bf(hv4.w) };
                *(us4*)(hD + ((size_t)b * T + t) * H + j0) = o;
            }
        }
    }
}

// ---------------- FC + softmax over time axis (dim=1) ----------------
__global__ __launch_bounds__(256) void fc_softmax(const unsigned short* __restrict__ h3F,
                                                  const unsigned short* __restrict__ h3B,
                                                  const float* __restrict__ fcw,
                                                  const float* __restrict__ fcb,
                                                  float* __restrict__ out) {
    constexpr int T = T_SZ;
    __shared__ float ez[T][6];
    __shared__ float ps[256][6];
    __shared__ float wf[6][16];
    __shared__ float bb[6];
    int b = blockIdx.x, tid = threadIdx.x;
    if (tid < 96) wf[tid >> 4][tid & 15] = fcw[tid];
    if (tid < 6) bb[tid] = fcb[tid];
    __syncthreads();
#pragma unroll
    for (int ii = 0; ii < 2; ii++) {
        int t = tid + ii * 256;
        short8 va = *(const short8*)(h3F + ((size_t)b * T + t) * 8);
        short8 vb = *(const short8*)(h3B + ((size_t)b * T + t) * 8);
        float hv[16];
#pragma unroll
        for (int k = 0; k < 8; k++) { hv[k] = bf2f((unsigned short)va[k]); hv[8 + k] = bf2f((unsigned short)vb[k]); }
#pragma unroll
        for (int cc = 0; cc < 6; cc++) {
            float z = bb[cc];
#pragma unroll
            for (int k = 0; k < 16; k++) z = fmaf(hv[k], wf[cc][k], z);
            ez[t][cc] = __expf(z);   // |z| <= ~4.5, no overflow; max-subtract not needed
        }
    }
    __syncthreads();
#pragma unroll
    for (int cc = 0; cc < 6; cc++) ps[tid][cc] = ez[tid][cc] + ez[tid + 256][cc];
    __syncthreads();
    for (int s = 128; s > 0; s >>= 1) {
        if (tid < s) {
#pragma unroll
            for (int cc = 0; cc < 6; cc++) ps[tid][cc] += ps[tid + s][cc];
        }
        __syncthreads();
    }
    float rs[6];
#pragma unroll
    for (int cc = 0; cc < 6; cc++) rs[cc] = rcp_(ps[0][cc]);
#pragma unroll
    for (int ii = 0; ii < 2; ii++) {
        int t = tid + ii * 256;
        float* op = out + ((size_t)b * T + t) * 6;
#pragma unroll
        for (int cc = 0; cc < 6; cc++) op[cc] = ez[t][cc] * rs[cc];
    }
}

// ---------------- launch ----------------
extern "C" void kernel_launch(void* const* d_in, const int* in_sizes, int n_in,
                              void* d_out, int out_size, void* d_ws, size_t ws_size,
                              hipStream_t stream) {
    const float* x     = (const float*)d_in[0];
    const float* whh1f = (const float*)d_in[2];
    const float* whh1b = (const float*)d_in[6];
    const float* whh2f = (const float*)d_in[10];
    const float* whh2b = (const float*)d_in[14];
    const float* whh3f = (const float*)d_in[18];
    const float* whh3b = (const float*)d_in[22];
    const float* fcw   = (const float*)d_in[25];
    const float* fcb   = (const float*)d_in[26];

    char* ws = (char*)d_ws;
    size_t off = 0;
    auto alloc = [&](size_t bytes) -> char* {
        char* p = ws + off; off += (bytes + 255) & ~(size_t)255; return p;
    };
    unsigned short* gxc = (unsigned short*)alloc((size_t)M_SZ * 256 * 2);
    unsigned short* h1F = (unsigned short*)alloc((size_t)M_SZ * 32 * 2);
    unsigned short* h1B = (unsigned short*)alloc((size_t)M_SZ * 32 * 2);
    unsigned short* h2F = (unsigned short*)alloc((size_t)M_SZ * 16 * 2);
    unsigned short* h2B = (unsigned short*)alloc((size_t)M_SZ * 16 * 2);
    unsigned short* h3F = (unsigned short*)alloc((size_t)M_SZ * 8 * 2);
    unsigned short* h3B = (unsigned short*)alloc((size_t)M_SZ * 8 * 2);
    unsigned short* wc1 = (unsigned short*)alloc(256 * 128 * 2);
    unsigned short* wc2 = (unsigned short*)alloc(128 * 64 * 2);
    unsigned short* wc3 = (unsigned short*)alloc(64 * 32 * 2);
    float* bs1 = (float*)alloc(256 * 4);
    float* bs2 = (float*)alloc(128 * 4);
    float* bs3 = (float*)alloc(64 * 4);

    prep_layer<<<16, 256, 0, stream>>>((const float*)d_in[1], (const float*)d_in[5],
                                       (const float*)d_in[3], (const float*)d_in[4],
                                       (const float*)d_in[7], (const float*)d_in[8],
                                       wc1, bs1, 128 * 128, 128);
    prep_layer<<<16, 256, 0, stream>>>((const float*)d_in[9], (const float*)d_in[13],
                                       (const float*)d_in[11], (const float*)d_in[12],
                                       (const float*)d_in[15], (const float*)d_in[16],
                                       wc2, bs2, 64 * 64, 64);
    prep_layer<<<16, 256, 0, stream>>>((const float*)d_in[17], (const float*)d_in[21],
                                       (const float*)d_in[19], (const float*)d_in[20],
                                       (const float*)d_in[23], (const float*)d_in[24],
                                       wc3, bs3, 32 * 32, 32);

    // Layer 1: K=128 (f32 x, cast fused), 8H=256
    gemm_gx_f32<128, 256><<<(M_SZ / 64) * 16 / 4, 256, 0, stream>>>(x, wc1, bs1, gxc);
    lstm_scan<32><<<256, 256, 0, stream>>>(gxc, whh1f, whh1b, h1F, h1B);
    // Layer 2: K=64 (split bf16 A), 8H=128
    gemm_gx_split<64, 128><<<(M_SZ / 64) * 8 / 4, 256, 0, stream>>>(h1F, h1B, wc2, bs2, gxc);
    lstm_scan<16><<<256, 256, 0, stream>>>(gxc, whh2f, whh2b, h2F, h2B);
    // Layer 3: K=32 (split bf16 A), 8H=64
    gemm_gx_split<32, 64><<<(M_SZ / 64) * 4 / 4, 256, 0, stream>>>(h2F, h2B, wc3, bs3, gxc);
    lstm_scan<8><<<256, 256, 0, stream>>>(gxc, whh3f, whh3b, h3F, h3B);

    fc_softmax<<<B_SZ, 256, 0, stream>>>(h3F, h3B, fcw, fcb, (float*)d_out);
}

// Round 4
// 671.084 us; speedup vs baseline: 1.3491x; 1.3491x over previous
//
#include <hip/hip_runtime.h>

// ---------------- common helpers ----------------
typedef __attribute__((ext_vector_type(8))) short short8;
typedef __attribute__((ext_vector_type(4))) float f32x4;
typedef __attribute__((ext_vector_type(4))) unsigned short us4;

#define B_SZ 512
#define T_SZ 512
#define M_SZ (B_SZ * T_SZ)   // 262144 rows

__device__ __forceinline__ unsigned short f2bf(float f) {
    union { float f; unsigned u; } v; v.f = f;
    unsigned r = v.u + 0x7FFFu + ((v.u >> 16) & 1u);   // RNE
    return (unsigned short)(r >> 16);
}
__device__ __forceinline__ float bf2f(unsigned short b) {
    union { unsigned u; float f; } v; v.u = ((unsigned)b) << 16;
    return v.f;
}
__device__ __forceinline__ float rcp_(float x) { return __builtin_amdgcn_rcpf(x); }
__device__ __forceinline__ float sigm_(float x) { return rcp_(1.f + __expf(-x)); }
__device__ __forceinline__ float tanh_s(float x) {   // overflow-safe tanh
    float ax = fminf(fabsf(x), 15.f);
    float e2 = __expf(2.f * ax);
    float t = (e2 - 1.f) * rcp_(e2 + 1.f);
    return x < 0.f ? -t : t;
}
__device__ __forceinline__ short8 cvt8(float4 a, float4 b) {
    short8 r;
    r[0] = (short)f2bf(a.x); r[1] = (short)f2bf(a.y); r[2] = (short)f2bf(a.z); r[3] = (short)f2bf(a.w);
    r[4] = (short)f2bf(b.x); r[5] = (short)f2bf(b.y); r[6] = (short)f2bf(b.z); r[7] = (short)f2bf(b.w);
    return r;
}
__device__ __forceinline__ float rdlane(float v, int lane) {
    return __int_as_float(__builtin_amdgcn_readlane(__float_as_int(v), lane));
}

// ---------------- weight prep: concat fwd/bwd w_ih -> bf16 [8H][K], bias = b_ih+b_hh ----------------
__global__ __launch_bounds__(256) void prep_layer(
        const float* __restrict__ wf, const float* __restrict__ wb,
        const float* __restrict__ bif, const float* __restrict__ bhf,
        const float* __restrict__ bib, const float* __restrict__ bhb,
        unsigned short* __restrict__ wcat, float* __restrict__ bias,
        int n /*4H*K*/, int fourH) {
    int stride = gridDim.x * blockDim.x;
    for (int i = blockIdx.x * blockDim.x + threadIdx.x; i < 2 * n; i += stride)
        wcat[i] = f2bf(i < n ? wf[i] : wb[i - n]);
    for (int i = blockIdx.x * blockDim.x + threadIdx.x; i < 2 * fourH; i += stride)
        bias[i] = (i < fourH) ? (bif[i] + bhf[i]) : (bib[i - fourH] + bhb[i - fourH]);
}

// ---------------- gx store: chunk-interleaved layout gxc[b][t>>3][g][t&7] ----------------
// Backward-gate rows (rev) are stored TIME-REVERSED so the scan always reads forward.
__device__ __forceinline__ void store_gx(unsigned short* __restrict__ outC, int N,
                                         int b, int tl, int col, bool rev,
                                         f32x4 acc, float bv) {
    if (!rev) {
        us4 v = { f2bf(acc[0]+bv), f2bf(acc[1]+bv), f2bf(acc[2]+bv), f2bf(acc[3]+bv) };
        *(us4*)(outC + (((size_t)b * 64 + (tl >> 3)) * (size_t)N + col) * 8 + (tl & 7)) = v;
    } else {
        int p = T_SZ - 4 - tl;
        us4 v = { f2bf(acc[3]+bv), f2bf(acc[2]+bv), f2bf(acc[1]+bv), f2bf(acc[0]+bv) };
        *(us4*)(outC + (((size_t)b * 64 + (p >> 3)) * (size_t)N + col) * 8 + (p & 7)) = v;
    }
}

// ---------------- layer-1 GEMM: A = x in f32 (cast fused), W bf16 [N][K] ----------------
template<int K, int N>
__global__ __launch_bounds__(256) void gemm_gx_f32(const float* __restrict__ A,
                                                   const unsigned short* __restrict__ W,
                                                   const float* __restrict__ bias,
                                                   unsigned short* __restrict__ outC) {
    constexpr int TN = N / 16;
    int slot = threadIdx.x >> 6, l = threadIdx.x & 63;
    int wv = blockIdx.x * 4 + slot;
    int tg = wv / TN, tn = wv % TN;
    int rowb = tg * 64;
    int col = tn * 16 + (l & 15);
    int kq = (l >> 4) * 8;
    f32x4 acc0 = {0,0,0,0}, acc1 = {0,0,0,0}, acc2 = {0,0,0,0}, acc3 = {0,0,0,0};
    const unsigned short* wp = W + (size_t)col * K + kq;
    const float* ap = A + ((size_t)rowb + (l & 15)) * K + kq;
#pragma unroll
    for (int kk = 0; kk < K; kk += 32) {
        short8 bfrag = *(const short8*)(wp + kk);
        short8 a0 = cvt8(*(const float4*)(ap + kk),                    *(const float4*)(ap + kk + 4));
        short8 a1 = cvt8(*(const float4*)(ap + (size_t)16*K + kk),     *(const float4*)(ap + (size_t)16*K + kk + 4));
        short8 a2 = cvt8(*(const float4*)(ap + (size_t)32*K + kk),     *(const float4*)(ap + (size_t)32*K + kk + 4));
        short8 a3 = cvt8(*(const float4*)(ap + (size_t)48*K + kk),     *(const float4*)(ap + (size_t)48*K + kk + 4));
        acc0 = __builtin_amdgcn_mfma_f32_16x16x32_bf16(a0, bfrag, acc0, 0, 0, 0);
        acc1 = __builtin_amdgcn_mfma_f32_16x16x32_bf16(a1, bfrag, acc1, 0, 0, 0);
        acc2 = __builtin_amdgcn_mfma_f32_16x16x32_bf16(a2, bfrag, acc2, 0, 0, 0);
        acc3 = __builtin_amdgcn_mfma_f32_16x16x32_bf16(a3, bfrag, acc3, 0, 0, 0);
    }
    float bv = bias[col];
    int b = rowb >> 9;
    int tbase = (rowb & 511) + (l >> 4) * 4;
    bool rev = (col >= N / 2);
    store_gx(outC, N, b, tbase,      col, rev, acc0, bv);
    store_gx(outC, N, b, tbase + 16, col, rev, acc1, bv);
    store_gx(outC, N, b, tbase + 32, col, rev, acc2, bv);
    store_gx(outC, N, b, tbase + 48, col, rev, acc3, bv);
}

// ---------------- layers 2/3 GEMM: A split into fwd/bwd bf16 halves [M][HALF] each ----------------
template<int K, int N>
__global__ __launch_bounds__(256) void gemm_gx_split(const unsigned short* __restrict__ AF,
                                                     const unsigned short* __restrict__ AB,
                                                     const unsigned short* __restrict__ W,
                                                     const float* __restrict__ bias,
                                                     unsigned short* __restrict__ outC) {
    constexpr int TN = N / 16;
    constexpr int HALF = K / 2;
    int slot = threadIdx.x >> 6, l = threadIdx.x & 63;
    int wv = blockIdx.x * 4 + slot;
    int tg = wv / TN, tn = wv % TN;
    int rowb = tg * 64;
    int col = tn * 16 + (l & 15);
    int kq = (l >> 4) * 8;
    f32x4 acc0 = {0,0,0,0}, acc1 = {0,0,0,0}, acc2 = {0,0,0,0}, acc3 = {0,0,0,0};
    const unsigned short* wp = W + (size_t)col * K + kq;
    size_t row = (size_t)rowb + (l & 15);
    const unsigned short* baseF = AF + row * HALF;
    const unsigned short* baseB = AB + row * HALF;
#pragma unroll
    for (int kk = 0; kk < K; kk += 32) {
        int ka = kq + kk;
        const unsigned short* pb = (ka < HALF) ? (baseF + ka) : (baseB + ka - HALF);
        short8 bfrag = *(const short8*)(wp + kk);
        short8 a0 = *(const short8*)(pb);
        short8 a1 = *(const short8*)(pb + (size_t)16 * HALF);
        short8 a2 = *(const short8*)(pb + (size_t)32 * HALF);
        short8 a3 = *(const short8*)(pb + (size_t)48 * HALF);
        acc0 = __builtin_amdgcn_mfma_f32_16x16x32_bf16(a0, bfrag, acc0, 0, 0, 0);
        acc1 = __builtin_amdgcn_mfma_f32_16x16x32_bf16(a1, bfrag, acc1, 0, 0, 0);
        acc2 = __builtin_amdgcn_mfma_f32_16x16x32_bf16(a2, bfrag, acc2, 0, 0, 0);
        acc3 = __builtin_amdgcn_mfma_f32_16x16x32_bf16(a3, bfrag, acc3, 0, 0, 0);
    }
    float bv = bias[col];
    int b = rowb >> 9;
    int tbase = (rowb & 511) + (l >> 4) * 4;
    bool rev = (col >= N / 2);
    store_gx(outC, N, b, tbase,      col, rev, acc0, bv);
    store_gx(outC, N, b, tbase + 16, col, rev, acc1, bv);
    store_gx(outC, N, b, tbase + 32, col, rev, acc2, bv);
    store_gx(outC, N, b, tbase + 48, col, rev, acc3, bv);
}

// ---------------- LSTM scan: one wave per (batch, direction) ----------------
// h broadcast via v_readlane (no LDS / DS-pipe on the serial chain).
// Gate split: lane jm<H handles rows {i_jm, g_jm}; lane jm+H handles {f_jm, o_jm};
// one shfl_xor(H) pair exchanges, both halves redundantly compute c,h so h is
// replicated in lanes 0..H-1 (and replicas) for the next step's readlane.
// gxc: bf16 [b][ch][8H][8]  (rows 0..4H-1 fwd, 4H..8H-1 bwd; bwd rows time-reversed)
// hF/hB: bf16 [b][t][H] at ORIGINAL time positions.
template<int H>
__global__ __launch_bounds__(256, 1) void lstm_scan(const unsigned short* __restrict__ gxc,
                                                    const float* __restrict__ whhf,
                                                    const float* __restrict__ whhb,
                                                    unsigned short* __restrict__ hF,
                                                    unsigned short* __restrict__ hB) {
    constexpr int T = T_SZ;
    constexpr int G4 = 4 * H, G8 = 8 * H;
    int l = threadIdx.x & 63, slot = threadIdx.x >> 6;
    int wv = blockIdx.x * 4 + slot;          // 0..1023
    int b = wv >> 1, dir = wv & 1;
    const float* whh = dir ? whhb : whhf;
    unsigned short* hD = dir ? hB : hF;
    __shared__ float hbuf[4][8][32];

    int jm = l & (2 * H - 1);                // replicated beyond 2H lanes
    bool half = (jm >= H);                   // 0: i,g rows; 1: f,o rows
    int rA = jm;                             // i (jm<H) or f (jm>=H)
    int rB = 2 * H + jm;                     // g (jm<H) or o (jm>=H)

    // recurrent weight rows pinned in VGPRs
    float wA[H], wB[H];
    {
        const float4* wrA = (const float4*)(whh + rA * H);
        const float4* wrB = (const float4*)(whh + rB * H);
#pragma unroll
        for (int k = 0; k < H / 4; k++) {
            float4 a = wrA[k], bq = wrB[k];
            wA[4*k]=a.x; wA[4*k+1]=a.y; wA[4*k+2]=a.z; wA[4*k+3]=a.w;
            wB[4*k]=bq.x; wB[4*k+1]=bq.y; wB[4*k+2]=bq.z; wB[4*k+3]=bq.w;
        }
    }

    const unsigned short* gpA = gxc + ((size_t)b * 64 * G8 + (size_t)dir * G4 + rA) * 8;
    const unsigned short* gpB = gxc + ((size_t)b * 64 * G8 + (size_t)dir * G4 + rB) * 8;

    float c = 0.f, h = 0.f;
    short8 bufA = *(const short8*)gpA;
    short8 bufB = *(const short8*)gpB;

    for (int ch = 0; ch < T / 8; ch++) {
        short8 curA = bufA, curB = bufB;
        if (ch + 1 < T / 8) {                // prefetch next 8-step chunk (coalesced 16B/lane)
            bufA = *(const short8*)(gpA + (size_t)(ch + 1) * G8 * 8);
            bufB = *(const short8*)(gpB + (size_t)(ch + 1) * G8 * 8);
        }
#pragma unroll
        for (int u = 0; u < 8; u++) {
            float g0 = bf2f((unsigned short)curA[u]);
            float g1 = bf2f((unsigned short)curB[u]);

            // W_hh · h via readlane broadcast (h_k valid in lane k, k<H)
            float a0=0,a1=0,a2=0,a3=0,b0=0,b1=0,b2=0,b3=0;
#pragma unroll
            for (int k = 0; k < H; k += 4) {
                float h0 = rdlane(h, k);
                float h1 = rdlane(h, k + 1);
                float h2 = rdlane(h, k + 2);
                float h3 = rdlane(h, k + 3);
                a0 = fmaf(wA[k],   h0, a0);  b0 = fmaf(wB[k],   h0, b0);
                a1 = fmaf(wA[k+1], h1, a1);  b1 = fmaf(wB[k+1], h1, b1);
                a2 = fmaf(wA[k+2], h2, a2);  b2 = fmaf(wB[k+2], h2, b2);
                a3 = fmaf(wA[k+3], h3, a3);  b3 = fmaf(wB[k+3], h3, b3);
            }
            g0 += (a0 + a1) + (a2 + a3);
            g1 += (b0 + b1) + (b2 + b3);

            // activations: aA = sigm (i or f); aB = tanh(g) for half=0, sigm(o) for half=1
            float aA = sigm_(g0);
            float g1c = fminf(fmaxf(g1, -15.f), 15.f);
            float ee = __expf(half ? -g1 : 2.f * g1c);
            float r = rcp_(1.f + ee);
            float aB = half ? r : (ee - 1.f) * r;
            float xA = __shfl_xor(aA, H, 64);
            float xB = __shfl_xor(aB, H, 64);
            float iv = half ? xA : aA;
            float fv = half ? aA : xA;
            float gv = half ? xB : aB;
            float ov = half ? aB : xB;

            c = fmaf(fv, c, iv * gv);
            h = ov * tanh_s(c);

            if (l < H) hbuf[slot][u][l] = h;   // stage for coalesced flush
        }
        // flush 8 steps of h: coalesced bf16 stores at original time positions
        {
            constexpr int GPT = H / 4;         // lane-groups per timestep
            if (l < 8 * GPT) {
                int tt = l / GPT;
                int j0 = (l % GPT) * 4;
                int us = dir ? (7 - tt) : tt;
                int t  = (dir ? (T - 8 - ch * 8) : ch * 8) + tt;
                float4 hv4 = *(const float4*)&hbuf[slot][us][j0];
                us4 o = { f2bf(hv4.x), f2bf(hv4.y), f2bf(hv4.z), f2bf(hv4.w) };
                *(us4*)(hD + ((size_t)b * T + t) * H + j0) = o;
            }
        }
    }
}

// ---------------- FC + softmax over time axis (dim=1) ----------------
__global__ __launch_bounds__(256) void fc_softmax(const unsigned short* __restrict__ h3F,
                                                  const unsigned short* __restrict__ h3B,
                                                  const float* __restrict__ fcw,
                                                  const float* __restrict__ fcb,
                                                  float* __restrict__ out) {
    constexpr int T = T_SZ;
    __shared__ float ez[T][6];
    __shared__ float ps[256][6];
    __shared__ float wf[6][16];
    __shared__ float bb[6];
    int b = blockIdx.x, tid = threadIdx.x;
    if (tid < 96) wf[tid >> 4][tid & 15] = fcw[tid];
    if (tid < 6) bb[tid] = fcb[tid];
    __syncthreads();
#pragma unroll
    for (int ii = 0; ii < 2; ii++) {
        int t = tid + ii * 256;
        short8 va = *(const short8*)(h3F + ((size_t)b * T + t) * 8);
        short8 vb = *(const short8*)(h3B + ((size_t)b * T + t) * 8);
        float hv[16];
#pragma unroll
        for (int k = 0; k < 8; k++) { hv[k] = bf2f((unsigned short)va[k]); hv[8 + k] = bf2f((unsigned short)vb[k]); }
#pragma unroll
        for (int cc = 0; cc < 6; cc++) {
            float z = bb[cc];
#pragma unroll
            for (int k = 0; k < 16; k++) z = fmaf(hv[k], wf[cc][k], z);
            ez[t][cc] = __expf(z);   // |z| <= ~4.5, no overflow; max-subtract not needed
        }
    }
    __syncthreads();
#pragma unroll
    for (int cc = 0; cc < 6; cc++) ps[tid][cc] = ez[tid][cc] + ez[tid + 256][cc];
    __syncthreads();
    for (int s = 128; s > 0; s >>= 1) {
        if (tid < s) {
#pragma unroll
            for (int cc = 0; cc < 6; cc++) ps[tid][cc] += ps[tid + s][cc];
        }
        __syncthreads();
    }
    float rs[6];
#pragma unroll
    for (int cc = 0; cc < 6; cc++) rs[cc] = rcp_(ps[0][cc]);
#pragma unroll
    for (int ii = 0; ii < 2; ii++) {
        int t = tid + ii * 256;
        float* op = out + ((size_t)b * T + t) * 6;
#pragma unroll
        for (int cc = 0; cc < 6; cc++) op[cc] = ez[t][cc] * rs[cc];
    }
}

// ---------------- launch ----------------
extern "C" void kernel_launch(void* const* d_in, const int* in_sizes, int n_in,
                              void* d_out, int out_size, void* d_ws, size_t ws_size,
                              hipStream_t stream) {
    const float* x     = (const float*)d_in[0];
    const float* whh1f = (const float*)d_in[2];
    const float* whh1b = (const float*)d_in[6];
    const float* whh2f = (const float*)d_in[10];
    const float* whh2b = (const float*)d_in[14];
    const float* whh3f = (const float*)d_in[18];
    const float* whh3b = (const float*)d_in[22];
    const float* fcw   = (const float*)d_in[25];
    const float* fcb   = (const float*)d_in[26];

    char* ws = (char*)d_ws;
    size_t off = 0;
    auto alloc = [&](size_t bytes) -> char* {
        char* p = ws + off; off += (bytes + 255) & ~(size_t)255; return p;
    };
    unsigned short* gxc = (unsigned short*)alloc((size_t)M_SZ * 256 * 2);
    unsigned short* h1F = (unsigned short*)alloc((size_t)M_SZ * 32 * 2);
    unsigned short* h1B = (unsigned short*)alloc((size_t)M_SZ * 32 * 2);
    unsigned short* h2F = (unsigned short*)alloc((size_t)M_SZ * 16 * 2);
    unsigned short* h2B = (unsigned short*)alloc((size_t)M_SZ * 16 * 2);
    unsigned short* h3F = (unsigned short*)alloc((size_t)M_SZ * 8 * 2);
    unsigned short* h3B = (unsigned short*)alloc((size_t)M_SZ * 8 * 2);
    unsigned short* wc1 = (unsigned short*)alloc(256 * 128 * 2);
    unsigned short* wc2 = (unsigned short*)alloc(128 * 64 * 2);
    unsigned short* wc3 = (unsigned short*)alloc(64 * 32 * 2);
    float* bs1 = (float*)alloc(256 * 4);
    float* bs2 = (float*)alloc(128 * 4);
    float* bs3 = (float*)alloc(64 * 4);

    prep_layer<<<16, 256, 0, stream>>>((const float*)d_in[1], (const float*)d_in[5],
                                       (const float*)d_in[3], (const float*)d_in[4],
                                       (const float*)d_in[7], (const float*)d_in[8],
                                       wc1, bs1, 128 * 128, 128);
    prep_layer<<<16, 256, 0, stream>>>((const float*)d_in[9], (const float*)d_in[13],
                                       (const float*)d_in[11], (const float*)d_in[12],
                                       (const float*)d_in[15], (const float*)d_in[16],
                                       wc2, bs2, 64 * 64, 64);
    prep_layer<<<16, 256, 0, stream>>>((const float*)d_in[17], (const float*)d_in[21],
                                       (const float*)d_in[19], (const float*)d_in[20],
                                       (const float*)d_in[23], (const float*)d_in[24],
                                       wc3, bs3, 32 * 32, 32);

    // Layer 1: K=128 (f32 x, cast fused), 8H=256
    gemm_gx_f32<128, 256><<<(M_SZ / 64) * 16 / 4, 256, 0, stream>>>(x, wc1, bs1, gxc);
    lstm_scan<32><<<256, 256, 0, stream>>>(gxc, whh1f, whh1b, h1F, h1B);
    // Layer 2: K=64 (split bf16 A), 8H=128
    gemm_gx_split<64, 128><<<(M_SZ / 64) * 8 / 4, 256, 0, stream>>>(h1F, h1B, wc2, bs2, gxc);
    lstm_scan<16><<<256, 256, 0, stream>>>(gxc, whh2f, whh2b, h2F, h2B);
    // Layer 3: K=32 (split bf16 A), 8H=64
    gemm_gx_split<32, 64><<<(M_SZ / 64) * 4 / 4, 256, 0, stream>>>(h2F, h2B, wc3, bs3, gxc);
    lstm_scan<8><<<256, 256, 0, stream>>>(gxc, whh3f, whh3b, h3F, h3B);

    fc_softmax<<<B_SZ, 256, 0, stream>>>(h3F, h3B, fcw, fcb, (float*)d_out);
}

// Round 5
// 484.597 us; speedup vs baseline: 1.8683x; 1.3848x over previous
//
#include <hip/hip_runtime.h>

// ---------------- common helpers ----------------
typedef __attribute__((ext_vector_type(8))) short short8;
typedef __attribute__((ext_vector_type(4))) float f32x4;
typedef __attribute__((ext_vector_type(4))) unsigned short us4;

#define B_SZ 512
#define T_SZ 512
#define M_SZ (B_SZ * T_SZ)   // 262144 rows

__device__ __forceinline__ unsigned short f2bf(float f) {
    union { float f; unsigned u; } v; v.f = f;
    unsigned r = v.u + 0x7FFFu + ((v.u >> 16) & 1u);   // RNE
    return (unsigned short)(r >> 16);
}
__device__ __forceinline__ float bf2f(unsigned short b) {
    union { unsigned u; float f; } v; v.u = ((unsigned)b) << 16;
    return v.f;
}
__device__ __forceinline__ float rcp_(float x) { return __builtin_amdgcn_rcpf(x); }
__device__ __forceinline__ float sigm_(float x) { return rcp_(1.f + __expf(-x)); }
__device__ __forceinline__ float tanh_s(float x) {   // overflow-safe tanh
    float ax = fminf(fabsf(x), 15.f);
    float e2 = __expf(2.f * ax);
    float t = (e2 - 1.f) * rcp_(e2 + 1.f);
    return x < 0.f ? -t : t;
}
__device__ __forceinline__ short8 cvt8(float4 a, float4 b) {
    short8 r;
    r[0] = (short)f2bf(a.x); r[1] = (short)f2bf(a.y); r[2] = (short)f2bf(a.z); r[3] = (short)f2bf(a.w);
    r[4] = (short)f2bf(b.x); r[5] = (short)f2bf(b.y); r[6] = (short)f2bf(b.z); r[7] = (short)f2bf(b.w);
    return r;
}
__device__ __forceinline__ float rdlane(float v, int lane) {
    return __int_as_float(__builtin_amdgcn_readlane(__float_as_int(v), lane));
}

// ---------------- weight prep: concat fwd/bwd w_ih -> bf16 [8H][K], bias = b_ih+b_hh ----------------
__global__ __launch_bounds__(256) void prep_layer(
        const float* __restrict__ wf, const float* __restrict__ wb,
        const float* __restrict__ bif, const float* __restrict__ bhf,
        const float* __restrict__ bib, const float* __restrict__ bhb,
        unsigned short* __restrict__ wcat, float* __restrict__ bias,
        int n /*4H*K*/, int fourH) {
    int stride = gridDim.x * blockDim.x;
    for (int i = blockIdx.x * blockDim.x + threadIdx.x; i < 2 * n; i += stride)
        wcat[i] = f2bf(i < n ? wf[i] : wb[i - n]);
    for (int i = blockIdx.x * blockDim.x + threadIdx.x; i < 2 * fourH; i += stride)
        bias[i] = (i < fourH) ? (bif[i] + bhf[i]) : (bib[i - fourH] + bhb[i - fourH]);
}

// ---------------- gx store: chunk-interleaved layout gxc[b][t>>3][g][t&7] ----------------
// Backward-gate rows (rev) are stored TIME-REVERSED so the scan always reads forward.
__device__ __forceinline__ void store_gx(unsigned short* __restrict__ outC, int N,
                                         int b, int tl, int col, bool rev,
                                         f32x4 acc, float bv) {
    if (!rev) {
        us4 v = { f2bf(acc[0]+bv), f2bf(acc[1]+bv), f2bf(acc[2]+bv), f2bf(acc[3]+bv) };
        *(us4*)(outC + (((size_t)b * 64 + (tl >> 3)) * (size_t)N + col) * 8 + (tl & 7)) = v;
    } else {
        int p = T_SZ - 4 - tl;
        us4 v = { f2bf(acc[3]+bv), f2bf(acc[2]+bv), f2bf(acc[1]+bv), f2bf(acc[0]+bv) };
        *(us4*)(outC + (((size_t)b * 64 + (p >> 3)) * (size_t)N + col) * 8 + (p & 7)) = v;
    }
}

// ---------------- layer-1 GEMM: LDS-staged, cast fused ONCE per element ----------------
// Block = 4 waves computes 64(M) x 256(N=all). A-tile (64x128 f32) staged to LDS
// as bf16 once; each wave computes a 64x64 quadrant (4 M-tiles x 4 N-tiles).
// LDS rows padded to 136 bf16 (272B stride -> 2-way bank aliasing, free).
__global__ __launch_bounds__(256) void gemm_gx_l1(const float* __restrict__ A,
                                                  const unsigned short* __restrict__ W,
                                                  const float* __restrict__ bias,
                                                  unsigned short* __restrict__ outC) {
    constexpr int K = 128, N = 256, LDW = 136;
    __shared__ unsigned short As[64 * LDW];   // 17408 B
    int tid = threadIdx.x;
    int slot = tid >> 6, l = tid & 63;
    int rowb = blockIdx.x * 64;

    // stage: 64x128 f32 -> bf16 LDS, each element exactly once, coalesced 32B/thread
    const float* abase = A + (size_t)rowb * K;
#pragma unroll
    for (int j = 0; j < 4; j++) {
        int flat = j * 2048 + tid * 8;
        int row = flat >> 7, k = flat & 127;
        float4 a = *(const float4*)(abase + flat);
        float4 bq = *(const float4*)(abase + flat + 4);
        *(short8*)&As[row * LDW + k] = cvt8(a, bq);
    }
    __syncthreads();

    int cl = l & 15, kq = (l >> 4) * 8;
    f32x4 acc[4][4];
#pragma unroll
    for (int mt = 0; mt < 4; mt++)
#pragma unroll
        for (int nt = 0; nt < 4; nt++) acc[mt][nt] = f32x4{0, 0, 0, 0};

    const unsigned short* wp0 = W + (size_t)(slot * 64 + cl) * K + kq;
#pragma unroll
    for (int kk = 0; kk < K; kk += 32) {
        short8 af[4];
#pragma unroll
        for (int mt = 0; mt < 4; mt++)
            af[mt] = *(const short8*)&As[(mt * 16 + cl) * LDW + kq + kk];
#pragma unroll
        for (int nt = 0; nt < 4; nt++) {
            short8 bfrag = *(const short8*)(wp0 + (size_t)nt * 16 * K + kk);
#pragma unroll
            for (int mt = 0; mt < 4; mt++)
                acc[mt][nt] = __builtin_amdgcn_mfma_f32_16x16x32_bf16(af[mt], bfrag, acc[mt][nt], 0, 0, 0);
        }
    }

    int b = rowb >> 9;
    int tbase = (rowb & 511) + (l >> 4) * 4;
    bool rev = (slot >= 2);                       // cols 0..127 fwd, 128..255 bwd
#pragma unroll
    for (int nt = 0; nt < 4; nt++) {
        int col = slot * 64 + nt * 16 + cl;
        float bv = bias[col];
#pragma unroll
        for (int mt = 0; mt < 4; mt++)
            store_gx(outC, N, b, tbase + mt * 16, col, rev, acc[mt][nt], bv);
    }
}

// ---------------- layers 2/3 GEMM: A split into fwd/bwd bf16 halves [M][HALF] each ----------------
template<int K, int N>
__global__ __launch_bounds__(256) void gemm_gx_split(const unsigned short* __restrict__ AF,
                                                     const unsigned short* __restrict__ AB,
                                                     const unsigned short* __restrict__ W,
                                                     const float* __restrict__ bias,
                                                     unsigned short* __restrict__ outC) {
    constexpr int TN = N / 16;
    constexpr int HALF = K / 2;
    int slot = threadIdx.x >> 6, l = threadIdx.x & 63;
    int wv = blockIdx.x * 4 + slot;
    int tg = wv / TN, tn = wv % TN;
    int rowb = tg * 64;
    int col = tn * 16 + (l & 15);
    int kq = (l >> 4) * 8;
    f32x4 acc0 = {0,0,0,0}, acc1 = {0,0,0,0}, acc2 = {0,0,0,0}, acc3 = {0,0,0,0};
    const unsigned short* wp = W + (size_t)col * K + kq;
    size_t row = (size_t)rowb + (l & 15);
    const unsigned short* baseF = AF + row * HALF;
    const unsigned short* baseB = AB + row * HALF;
#pragma unroll
    for (int kk = 0; kk < K; kk += 32) {
        int ka = kq + kk;
        const unsigned short* pb = (ka < HALF) ? (baseF + ka) : (baseB + ka - HALF);
        short8 bfrag = *(const short8*)(wp + kk);
        short8 a0 = *(const short8*)(pb);
        short8 a1 = *(const short8*)(pb + (size_t)16 * HALF);
        short8 a2 = *(const short8*)(pb + (size_t)32 * HALF);
        short8 a3 = *(const short8*)(pb + (size_t)48 * HALF);
        acc0 = __builtin_amdgcn_mfma_f32_16x16x32_bf16(a0, bfrag, acc0, 0, 0, 0);
        acc1 = __builtin_amdgcn_mfma_f32_16x16x32_bf16(a1, bfrag, acc1, 0, 0, 0);
        acc2 = __builtin_amdgcn_mfma_f32_16x16x32_bf16(a2, bfrag, acc2, 0, 0, 0);
        acc3 = __builtin_amdgcn_mfma_f32_16x16x32_bf16(a3, bfrag, acc3, 0, 0, 0);
    }
    float bv = bias[col];
    int b = rowb >> 9;
    int tbase = (rowb & 511) + (l >> 4) * 4;
    bool rev = (col >= N / 2);
    store_gx(outC, N, b, tbase,      col, rev, acc0, bv);
    store_gx(outC, N, b, tbase + 16, col, rev, acc1, bv);
    store_gx(outC, N, b, tbase + 32, col, rev, acc2, bv);
    store_gx(outC, N, b, tbase + 48, col, rev, acc3, bv);
}

// ---------------- LSTM scan: one wave per (batch, direction) ----------------
// h broadcast via v_readlane (no LDS / DS-pipe on the serial chain).
// Gate split: lane jm<H handles rows {i_jm, g_jm}; lane jm+H handles {f_jm, o_jm};
// one shfl_xor(H) pair exchanges, both halves redundantly compute c,h so h is
// replicated in lanes 0..H-1 (and replicas) for the next step's readlane.
// gxc: bf16 [b][ch][8H][8]  (rows 0..4H-1 fwd, 4H..8H-1 bwd; bwd rows time-reversed)
// hF/hB: bf16 [b][t][H] at ORIGINAL time positions.
template<int H>
__global__ __launch_bounds__(256, 1) void lstm_scan(const unsigned short* __restrict__ gxc,
                                                    const float* __restrict__ whhf,
                                                    const float* __restrict__ whhb,
                                                    unsigned short* __restrict__ hF,
                                                    unsigned short* __restrict__ hB) {
    constexpr int T = T_SZ;
    constexpr int G4 = 4 * H, G8 = 8 * H;
    int l = threadIdx.x & 63, slot = threadIdx.x >> 6;
    int wv = blockIdx.x * 4 + slot;          // 0..1023
    int b = wv >> 1, dir = wv & 1;
    const float* whh = dir ? whhb : whhf;
    unsigned short* hD = dir ? hB : hF;
    __shared__ float hbuf[4][8][32];

    int jm = l & (2 * H - 1);                // replicated beyond 2H lanes
    bool half = (jm >= H);                   // 0: i,g rows; 1: f,o rows
    int rA = jm;                             // i (jm<H) or f (jm>=H)
    int rB = 2 * H + jm;                     // g (jm<H) or o (jm>=H)

    // recurrent weight rows pinned in VGPRs
    float wA[H], wB[H];
    {
        const float4* wrA = (const float4*)(whh + rA * H);
        const float4* wrB = (const float4*)(whh + rB * H);
#pragma unroll
        for (int k = 0; k < H / 4; k++) {
            float4 a = wrA[k], bq = wrB[k];
            wA[4*k]=a.x; wA[4*k+1]=a.y; wA[4*k+2]=a.z; wA[4*k+3]=a.w;
            wB[4*k]=bq.x; wB[4*k+1]=bq.y; wB[4*k+2]=bq.z; wB[4*k+3]=bq.w;
        }
    }

    const unsigned short* gpA = gxc + ((size_t)b * 64 * G8 + (size_t)dir * G4 + rA) * 8;
    const unsigned short* gpB = gxc + ((size_t)b * 64 * G8 + (size_t)dir * G4 + rB) * 8;

    float c = 0.f, h = 0.f;
    short8 bufA = *(const short8*)gpA;
    short8 bufB = *(const short8*)gpB;

    for (int ch = 0; ch < T / 8; ch++) {
        short8 curA = bufA, curB = bufB;
        if (ch + 1 < T / 8) {                // prefetch next 8-step chunk (coalesced 16B/lane)
            bufA = *(const short8*)(gpA + (size_t)(ch + 1) * G8 * 8);
            bufB = *(const short8*)(gpB + (size_t)(ch + 1) * G8 * 8);
        }
#pragma unroll
        for (int u = 0; u < 8; u++) {
            float g0 = bf2f((unsigned short)curA[u]);
            float g1 = bf2f((unsigned short)curB[u]);

            // W_hh · h via readlane broadcast (h_k valid in lane k, k<H)
            float a0=0,a1=0,a2=0,a3=0,b0=0,b1=0,b2=0,b3=0;
#pragma unroll
            for (int k = 0; k < H; k += 4) {
                float h0 = rdlane(h, k);
                float h1 = rdlane(h, k + 1);
                float h2 = rdlane(h, k + 2);
                float h3 = rdlane(h, k + 3);
                a0 = fmaf(wA[k],   h0, a0);  b0 = fmaf(wB[k],   h0, b0);
                a1 = fmaf(wA[k+1], h1, a1);  b1 = fmaf(wB[k+1], h1, b1);
                a2 = fmaf(wA[k+2], h2, a2);  b2 = fmaf(wB[k+2], h2, b2);
                a3 = fmaf(wA[k+3], h3, a3);  b3 = fmaf(wB[k+3], h3, b3);
            }
            g0 += (a0 + a1) + (a2 + a3);
            g1 += (b0 + b1) + (b2 + b3);

            // activations: aA = sigm (i or f); aB = tanh(g) for half=0, sigm(o) for half=1
            float aA = sigm_(g0);
            float g1c = fminf(fmaxf(g1, -15.f), 15.f);
            float ee = __expf(half ? -g1 : 2.f * g1c);
            float r = rcp_(1.f + ee);
            float aB = half ? r : (ee - 1.f) * r;
            float xA = __shfl_xor(aA, H, 64);
            float xB = __shfl_xor(aB, H, 64);
            float iv = half ? xA : aA;
            float fv = half ? aA : xA;
            float gv = half ? xB : aB;
            float ov = half ? aB : xB;

            c = fmaf(fv, c, iv * gv);
            h = ov * tanh_s(c);

            if (l < H) hbuf[slot][u][l] = h;   // stage for coalesced flush
        }
        // flush 8 steps of h: coalesced bf16 stores at original time positions
        {
            constexpr int GPT = H / 4;         // lane-groups per timestep
            if (l < 8 * GPT) {
                int tt = l / GPT;
                int j0 = (l % GPT) * 4;
                int us = dir ? (7 - tt) : tt;
                int t  = (dir ? (T - 8 - ch * 8) : ch * 8) + tt;
                float4 hv4 = *(const float4*)&hbuf[slot][us][j0];
                us4 o = { f2bf(hv4.x), f2bf(hv4.y), f2bf(hv4.z), f2bf(hv4.w) };
                *(us4*)(hD + ((size_t)b * T + t) * H + j0) = o;
            }
        }
    }
}

// ---------------- FC + softmax over time axis (dim=1) ----------------
__global__ __launch_bounds__(256) void fc_softmax(const unsigned short* __restrict__ h3F,
                                                  const unsigned short* __restrict__ h3B,
                                                  const float* __restrict__ fcw,
                                                  const float* __restrict__ fcb,
                                                  float* __restrict__ out) {
    constexpr int T = T_SZ;
    __shared__ float ez[T][6];
    __shared__ float ps[256][6];
    __shared__ float wf[6][16];
    __shared__ float bb[6];
    int b = blockIdx.x, tid = threadIdx.x;
    if (tid < 96) wf[tid >> 4][tid & 15] = fcw[tid];
    if (tid < 6) bb[tid] = fcb[tid];
    __syncthreads();
#pragma unroll
    for (int ii = 0; ii < 2; ii++) {
        int t = tid + ii * 256;
        short8 va = *(const short8*)(h3F + ((size_t)b * T + t) * 8);
        short8 vb = *(const short8*)(h3B + ((size_t)b * T + t) * 8);
        float hv[16];
#pragma unroll
        for (int k = 0; k < 8; k++) { hv[k] = bf2f((unsigned short)va[k]); hv[8 + k] = bf2f((unsigned short)vb[k]); }
#pragma unroll
        for (int cc = 0; cc < 6; cc++) {
            float z = bb[cc];
#pragma unroll
            for (int k = 0; k < 16; k++) z = fmaf(hv[k], wf[cc][k], z);
            ez[t][cc] = __expf(z);   // |z| <= ~4.5, no overflow; max-subtract not needed
        }
    }
    __syncthreads();
#pragma unroll
    for (int cc = 0; cc < 6; cc++) ps[tid][cc] = ez[tid][cc] + ez[tid + 256][cc];
    __syncthreads();
    for (int s = 128; s > 0; s >>= 1) {
        if (tid < s) {
#pragma unroll
            for (int cc = 0; cc < 6; cc++) ps[tid][cc] += ps[tid + s][cc];
        }
        __syncthreads();
    }
    float rs[6];
#pragma unroll
    for (int cc = 0; cc < 6; cc++) rs[cc] = rcp_(ps[0][cc]);
#pragma unroll
    for (int ii = 0; ii < 2; ii++) {
        int t = tid + ii * 256;
        float* op = out + ((size_t)b * T + t) * 6;
#pragma unroll
        for (int cc = 0; cc < 6; cc++) op[cc] = ez[t][cc] * rs[cc];
    }
}

// ---------------- launch ----------------
extern "C" void kernel_launch(void* const* d_in, const int* in_sizes, int n_in,
                              void* d_out, int out_size, void* d_ws, size_t ws_size,
                              hipStream_t stream) {
    const float* x     = (const float*)d_in[0];
    const float* whh1f = (const float*)d_in[2];
    const float* whh1b = (const float*)d_in[6];
    const float* whh2f = (const float*)d_in[10];
    const float* whh2b = (const float*)d_in[14];
    const float* whh3f = (const float*)d_in[18];
    const float* whh3b = (const float*)d_in[22];
    const float* fcw   = (const float*)d_in[25];
    const float* fcb   = (const float*)d_in[26];

    char* ws = (char*)d_ws;
    size_t off = 0;
    auto alloc = [&](size_t bytes) -> char* {
        char* p = ws + off; off += (bytes + 255) & ~(size_t)255; return p;
    };
    unsigned short* gxc = (unsigned short*)alloc((size_t)M_SZ * 256 * 2);
    unsigned short* h1F = (unsigned short*)alloc((size_t)M_SZ * 32 * 2);
    unsigned short* h1B = (unsigned short*)alloc((size_t)M_SZ * 32 * 2);
    unsigned short* h2F = (unsigned short*)alloc((size_t)M_SZ * 16 * 2);
    unsigned short* h2B = (unsigned short*)alloc((size_t)M_SZ * 16 * 2);
    unsigned short* h3F = (unsigned short*)alloc((size_t)M_SZ * 8 * 2);
    unsigned short* h3B = (unsigned short*)alloc((size_t)M_SZ * 8 * 2);
    unsigned short* wc1 = (unsigned short*)alloc(256 * 128 * 2);
    unsigned short* wc2 = (unsigned short*)alloc(128 * 64 * 2);
    unsigned short* wc3 = (unsigned short*)alloc(64 * 32 * 2);
    float* bs1 = (float*)alloc(256 * 4);
    float* bs2 = (float*)alloc(128 * 4);
    float* bs3 = (float*)alloc(64 * 4);

    prep_layer<<<16, 256, 0, stream>>>((const float*)d_in[1], (const float*)d_in[5],
                                       (const float*)d_in[3], (const float*)d_in[4],
                                       (const float*)d_in[7], (const float*)d_in[8],
                                       wc1, bs1, 128 * 128, 128);
    prep_layer<<<16, 256, 0, stream>>>((const float*)d_in[9], (const float*)d_in[13],
                                       (const float*)d_in[11], (const float*)d_in[12],
                                       (const float*)d_in[15], (const float*)d_in[16],
                                       wc2, bs2, 64 * 64, 64);
    prep_layer<<<16, 256, 0, stream>>>((const float*)d_in[17], (const float*)d_in[21],
                                       (const float*)d_in[19], (const float*)d_in[20],
                                       (const float*)d_in[23], (const float*)d_in[24],
                                       wc3, bs3, 32 * 32, 32);

    // Layer 1: K=128 (f32 x, cast fused once via LDS staging), 8H=256
    gemm_gx_l1<<<M_SZ / 64, 256, 0, stream>>>(x, wc1, bs1, gxc);
    lstm_scan<32><<<256, 256, 0, stream>>>(gxc, whh1f, whh1b, h1F, h1B);
    // Layer 2: K=64 (split bf16 A), 8H=128
    gemm_gx_split<64, 128><<<(M_SZ / 64) * 8 / 4, 256, 0, stream>>>(h1F, h1B, wc2, bs2, gxc);
    lstm_scan<16><<<256, 256, 0, stream>>>(gxc, whh2f, whh2b, h2F, h2B);
    // Layer 3: K=32 (split bf16 A), 8H=64
    gemm_gx_split<32, 64><<<(M_SZ / 64) * 4 / 4, 256, 0, stream>>>(h2F, h2B, wc3, bs3, gxc);
    lstm_scan<8><<<256, 256, 0, stream>>>(gxc, whh3f, whh3b, h3F, h3B);

    fc_softmax<<<B_SZ, 256, 0, stream>>>(h3F, h3B, fcw, fcb, (float*)d_out);
}